// Round 9
// baseline (384.063 us; speedup 1.0000x reference)
//
#include <hip/hip_runtime.h>
#include <hip/hip_bf16.h>
#include <math.h>

typedef __bf16 bf16x8 __attribute__((ext_vector_type(8)));
typedef __bf16 bf16x4 __attribute__((ext_vector_type(4)));
typedef float  f32x4  __attribute__((ext_vector_type(4)));

constexpr int Nn = 8192;   // B*S
constexpr int Dd = 256;    // feature dim
constexpr float LOG2E     = 1.4426950408889634f;
constexpr float SIM_SCALE = 20.0f * LOG2E;   // (1/tau)*log2(e), tau=0.05
constexpr float SIM_BIAS  = -20.0f * LOG2E;  // fixed max = 1/tau (|q.k|<=1)
constexpr unsigned int NBLK = 64 * 64;       // gemm grid size

// ---------------------------------------------------------------------------
// Kernel 1: L2-normalize rows -> bf16; init cbias / g_all / g_pos / done.
// ---------------------------------------------------------------------------
__global__ __launch_bounds__(256) void prep_kernel(const float* __restrict__ logits,
                                                   const float* __restrict__ labels,
                                                   const int* __restrict__ pad,
                                                   __bf16* __restrict__ qb,
                                                   __bf16* __restrict__ kb,
                                                   float* __restrict__ cbias,
                                                   float* __restrict__ g_all,
                                                   float* __restrict__ g_pos,
                                                   unsigned int* __restrict__ done) {
  const int j = blockIdx.x * 256 + threadIdx.x;
  if (j < Nn) {
    cbias[j] = pad[j] ? 0.0f : -1e30f;
    g_all[j] = 0.0f;
    g_pos[j] = 0.0f;
  }
  if (j == 0) *done = 0u;

  const int gw   = (blockIdx.x * 256 + threadIdx.x) >> 6;
  const int lane = threadIdx.x & 63;
  const float* src;
  __bf16* dst;
  int row;
  if (gw < Nn) { src = logits; dst = qb; row = gw; }
  else         { src = labels; dst = kb; row = gw - Nn; }

  const float4 v = *reinterpret_cast<const float4*>(src + (size_t)row * Dd + lane * 4);
  float ss = v.x * v.x + v.y * v.y + v.z * v.z + v.w * v.w;
#pragma unroll
  for (int m = 32; m >= 1; m >>= 1) ss += __shfl_xor(ss, m);
  const float scale = 1.0f / fmaxf(sqrtf(ss), 1e-12f);

  bf16x4 o;
  o[0] = (__bf16)(v.x * scale);
  o[1] = (__bf16)(v.y * scale);
  o[2] = (__bf16)(v.z * scale);
  o[3] = (__bf16)(v.w * scale);
  *reinterpret_cast<bf16x4*>(dst + (size_t)row * Dd + lane * 4) = o;
}

// ---------------------------------------------------------------------------
// Kernel 2: fused sim = Q K^T / tau + dual exp-sum epilogue (all & pos) +
// last-block finalize (loss reduction) via device-scope done counter.
// K-loop identical to R4-R8 (0 conflicts): BK=64, XOR-swizzled LDS
// (group' = c ^ (row&7)), VGPR staging. Epilogue identical to R6 (59.9 us,
// absmax 0). Finalize: release fence + atomic counter; 4096th block reads
// g_all/g_pos with agent-scope atomic loads (XCD-coherent) and writes out.
// ---------------------------------------------------------------------------
__global__ __launch_bounds__(256) void gemm_lse_kernel(const __bf16* __restrict__ qb,
                                                       const __bf16* __restrict__ kb,
                                                       const float* __restrict__ cbias,
                                                       const int* __restrict__ ad,
                                                       float* __restrict__ g_all,
                                                       float* __restrict__ g_pos,
                                                       unsigned int* __restrict__ done,
                                                       float* __restrict__ out) {
  __shared__ __bf16 smem[2 * 128 * 64];  // 32 KiB: As | Bs, reused by epilogue
  __bf16* As = smem;
  __bf16* Bs = smem + 128 * 64;
  float* redA = reinterpret_cast<float*>(smem);         // 128 x 32 partials
  float* redP = reinterpret_cast<float*>(smem) + 4096;  // 128 x 32 partials

  const int tid  = threadIdx.x;
  const int lane = tid & 63;
  const int w    = tid >> 6;
  const int wrow = (w >> 1) * 64;
  const int wcol = (w & 1) * 64;
  const int lq   = lane & 15;
  const int qd   = lane >> 4;
  const int rowBase = blockIdx.x * 128;
  const int colBase = blockIdx.y * 128;

  const int sr0 = tid >> 3;
  const int c0  = tid & 7;

  f32x4 c[4][4];
#pragma unroll
  for (int mt = 0; mt < 4; ++mt)
#pragma unroll
    for (int nt = 0; nt < 4; ++nt)
      c[mt][nt] = (f32x4){0.f, 0.f, 0.f, 0.f};

  for (int kk = 0; kk < 4; ++kk) {
    const int kOff = kk * 64;
    __syncthreads();
#pragma unroll
    for (int i = 0; i < 4; ++i) {
      const int sr  = sr0 + i * 32;
      const int dst = sr * 64 + (c0 ^ (sr & 7)) * 8;
      *reinterpret_cast<float4*>(&As[dst]) =
          *reinterpret_cast<const float4*>(qb + (size_t)(rowBase + sr) * Dd + kOff + c0 * 8);
      *reinterpret_cast<float4*>(&Bs[dst]) =
          *reinterpret_cast<const float4*>(kb + (size_t)(colBase + sr) * Dd + kOff + c0 * 8);
    }
    __syncthreads();

#pragma unroll
    for (int kq = 0; kq < 2; ++kq) {
      bf16x8 af[4], bfq[4];
      const int lg = kq * 4 + qd;
#pragma unroll
      for (int mt = 0; mt < 4; ++mt) {
        const int r = wrow + mt * 16 + lq;
        af[mt] = *reinterpret_cast<const bf16x8*>(&As[r * 64 + (lg ^ (r & 7)) * 8]);
      }
#pragma unroll
      for (int nt = 0; nt < 4; ++nt) {
        const int r = wcol + nt * 16 + lq;
        bfq[nt] = *reinterpret_cast<const bf16x8*>(&Bs[r * 64 + (lg ^ (r & 7)) * 8]);
      }
#pragma unroll
      for (int mt = 0; mt < 4; ++mt)
#pragma unroll
        for (int nt = 0; nt < 4; ++nt)
          c[mt][nt] = __builtin_amdgcn_mfma_f32_16x16x32_bf16(af[mt], bfq[nt], c[mt][nt], 0, 0, 0);
    }
  }

  // ---- epilogue (R6-identical): e = exp(sim-20); pos gated by ad match ----
  float colB[4];
  int colAd[4];
#pragma unroll
  for (int nt = 0; nt < 4; ++nt) {
    const int col = colBase + wcol + nt * 16 + lq;
    colB[nt]  = SIM_BIAS + cbias[col];
    colAd[nt] = ad[col];
  }

  __syncthreads();  // all waves done with As/Bs before reuse as partials

  const int idx = (w & 1) * 16 + lq;   // 32 partials per row
  const int g   = idx >> 2;
  const int gi  = idx & 3;

#pragma unroll
  for (int mt = 0; mt < 4; ++mt) {
#pragma unroll
    for (int r = 0; r < 4; ++r) {
      const int row   = wrow + mt * 16 + qd * 4 + r;
      const int rowAd = ad[rowBase + row];
      float a = 0.f, p = 0.f;
#pragma unroll
      for (int nt = 0; nt < 4; ++nt) {
        const float e = __builtin_amdgcn_exp2f(fmaf(c[mt][nt][r], SIM_SCALE, colB[nt]));
        a += e;
        p += (colAd[nt] == rowAd) ? e : 0.f;
      }
      const int off = row * 32 + ((g ^ (row & 7)) << 2) + gi;
      redA[off] = a;
      redP[off] = p;
    }
  }
  __syncthreads();

  if (tid < 128) {
    const int row = tid;
    float a = 0.f, p = 0.f;
#pragma unroll
    for (int gg = 0; gg < 8; ++gg) {
      const int off = row * 32 + ((gg ^ (row & 7)) << 2);
      const f32x4 va = *reinterpret_cast<const f32x4*>(&redA[off]);
      const f32x4 vp = *reinterpret_cast<const f32x4*>(&redP[off]);
      a += (va[0] + va[1]) + (va[2] + va[3]);
      p += (vp[0] + vp[1]) + (vp[2] + vp[3]);
    }
    atomicAdd(&g_all[rowBase + row], a);
    atomicAdd(&g_pos[rowBase + row], p);
  }

  // ---- finalize: last block to finish computes the loss ----
  __threadfence();                       // release our atomics before counting
  __shared__ int isLast;
  if (tid == 0) isLast = (atomicAdd(done, 1u) == NBLK - 1u) ? 1 : 0;
  __syncthreads();
  if (isLast) {
    __threadfence();                     // acquire all blocks' atomics
    __shared__ float sS[4], sC[4];
    float s = 0.f, cctr = 0.f;
    for (int i = tid; i < Nn; i += 256) {
      if (cbias[i] == 0.0f) {            // valid row
        const float a = __hip_atomic_load(&g_all[i], __ATOMIC_RELAXED, __HIP_MEMORY_SCOPE_AGENT);
        const float p = __hip_atomic_load(&g_pos[i], __ATOMIC_RELAXED, __HIP_MEMORY_SCOPE_AGENT);
        s += __logf(a) - __logf(p);
        cctr += 1.0f;
      }
    }
#pragma unroll
    for (int m = 32; m >= 1; m >>= 1) {
      s += __shfl_xor(s, m);
      cctr += __shfl_xor(cctr, m);
    }
    if (lane == 0) { sS[w] = s; sC[w] = cctr; }
    __syncthreads();
    if (tid == 0) {
      const float S = sS[0] + sS[1] + sS[2] + sS[3];
      const float C = sC[0] + sC[1] + sC[2] + sC[3];
      out[0] = S / fmaxf(C, 1.0f);
    }
  }
}

extern "C" void kernel_launch(void* const* d_in, const int* in_sizes, int n_in,
                              void* d_out, int out_size, void* d_ws, size_t ws_size,
                              hipStream_t stream) {
  const float* logits = (const float*)d_in[0];
  const float* labels = (const float*)d_in[1];
  const int*   pad    = (const int*)d_in[2];
  const int*   ad     = (const int*)d_in[3];

  char* ws = (char*)d_ws;
  __bf16* qb   = (__bf16*)(ws);                 // 4 MiB
  __bf16* kb   = (__bf16*)(ws + 4194304);       // 4 MiB
  float*  cb   = (float*)(ws + 8388608);        // 32 KiB
  float*  gAll = (float*)(ws + 8421376);        // 32 KiB
  float*  gPos = (float*)(ws + 8454144);        // 32 KiB
  unsigned int* done = (unsigned int*)(ws + 8486912);
  float*  out  = (float*)d_out;

  prep_kernel<<<4096, 256, 0, stream>>>(logits, labels, pad, qb, kb, cb, gAll, gPos, done);
  gemm_lse_kernel<<<dim3(64, 64), 256, 0, stream>>>(qb, kb, cb, ad, gAll, gPos, done, out);
}

// Round 10
// 168.918 us; speedup vs baseline: 2.2737x; 2.2737x over previous
//
#include <hip/hip_runtime.h>
#include <hip/hip_bf16.h>
#include <math.h>

typedef __bf16 bf16x8 __attribute__((ext_vector_type(8)));
typedef __bf16 bf16x4 __attribute__((ext_vector_type(4)));
typedef float  f32x4  __attribute__((ext_vector_type(4)));

constexpr int Nn = 8192;   // B*S
constexpr int Dd = 256;    // feature dim
constexpr float LOG2E     = 1.4426950408889634f;
constexpr float SIM_SCALE = 20.0f * LOG2E;   // (1/tau)*log2(e), tau=0.05
constexpr float SIM_BIAS  = -20.0f * LOG2E;  // fixed max = 1/tau (|q.k|<=1)
constexpr unsigned int NBLK = 64 * 64;       // gemm grid size

// ---------------------------------------------------------------------------
// Kernel 1: L2-normalize rows -> bf16; init cbias / g_all / g_pos / done.
// ---------------------------------------------------------------------------
__global__ __launch_bounds__(256) void prep_kernel(const float* __restrict__ logits,
                                                   const float* __restrict__ labels,
                                                   const int* __restrict__ pad,
                                                   __bf16* __restrict__ qb,
                                                   __bf16* __restrict__ kb,
                                                   float* __restrict__ cbias,
                                                   float* __restrict__ g_all,
                                                   float* __restrict__ g_pos,
                                                   unsigned int* __restrict__ done) {
  const int j = blockIdx.x * 256 + threadIdx.x;
  if (j < Nn) {
    cbias[j] = pad[j] ? 0.0f : -1e30f;
    g_all[j] = 0.0f;
    g_pos[j] = 0.0f;
  }
  if (j == 0) *done = 0u;

  const int gw   = (blockIdx.x * 256 + threadIdx.x) >> 6;
  const int lane = threadIdx.x & 63;
  const float* src;
  __bf16* dst;
  int row;
  if (gw < Nn) { src = logits; dst = qb; row = gw; }
  else         { src = labels; dst = kb; row = gw - Nn; }

  const float4 v = *reinterpret_cast<const float4*>(src + (size_t)row * Dd + lane * 4);
  float ss = v.x * v.x + v.y * v.y + v.z * v.z + v.w * v.w;
#pragma unroll
  for (int m = 32; m >= 1; m >>= 1) ss += __shfl_xor(ss, m);
  const float scale = 1.0f / fmaxf(sqrtf(ss), 1e-12f);

  bf16x4 o;
  o[0] = (__bf16)(v.x * scale);
  o[1] = (__bf16)(v.y * scale);
  o[2] = (__bf16)(v.z * scale);
  o[3] = (__bf16)(v.w * scale);
  *reinterpret_cast<bf16x4*>(dst + (size_t)row * Dd + lane * 4) = o;
}

// ---------------------------------------------------------------------------
// Kernel 2: fused sim = Q K^T / tau + dual exp-sum epilogue (all & pos) +
// last-block finalize. NO __threadfence (R9's 6x regression: agent fences
// lower to buffer_wbl2/buffer_inv -- 16k full-L2 flushes). Ordering instead:
// __syncthreads() drains vmcnt(0) per wave => this block's g_all/g_pos
// atomicAdds are COMPLETE at the device-coherent point before tid0 issues
// the done increment (device-scope atomics are cross-XCD coherent, m20/G16).
// Last block reads accumulators via agent-scope relaxed atomic loads.
// ---------------------------------------------------------------------------
__global__ __launch_bounds__(256) void gemm_lse_kernel(const __bf16* __restrict__ qb,
                                                       const __bf16* __restrict__ kb,
                                                       const float* __restrict__ cbias,
                                                       const int* __restrict__ ad,
                                                       float* __restrict__ g_all,
                                                       float* __restrict__ g_pos,
                                                       unsigned int* __restrict__ done,
                                                       float* __restrict__ out) {
  __shared__ __bf16 smem[2 * 128 * 64];  // 32 KiB: As | Bs, reused by epilogue
  __bf16* As = smem;
  __bf16* Bs = smem + 128 * 64;
  float* redA = reinterpret_cast<float*>(smem);         // 128 x 32 partials
  float* redP = reinterpret_cast<float*>(smem) + 4096;  // 128 x 32 partials

  const int tid  = threadIdx.x;
  const int lane = tid & 63;
  const int w    = tid >> 6;
  const int wrow = (w >> 1) * 64;
  const int wcol = (w & 1) * 64;
  const int lq   = lane & 15;
  const int qd   = lane >> 4;
  const int rowBase = blockIdx.x * 128;
  const int colBase = blockIdx.y * 128;

  const int sr0 = tid >> 3;
  const int c0  = tid & 7;

  f32x4 c[4][4];
#pragma unroll
  for (int mt = 0; mt < 4; ++mt)
#pragma unroll
    for (int nt = 0; nt < 4; ++nt)
      c[mt][nt] = (f32x4){0.f, 0.f, 0.f, 0.f};

  for (int kk = 0; kk < 4; ++kk) {
    const int kOff = kk * 64;
    __syncthreads();
#pragma unroll
    for (int i = 0; i < 4; ++i) {
      const int sr  = sr0 + i * 32;
      const int dst = sr * 64 + (c0 ^ (sr & 7)) * 8;
      *reinterpret_cast<float4*>(&As[dst]) =
          *reinterpret_cast<const float4*>(qb + (size_t)(rowBase + sr) * Dd + kOff + c0 * 8);
      *reinterpret_cast<float4*>(&Bs[dst]) =
          *reinterpret_cast<const float4*>(kb + (size_t)(colBase + sr) * Dd + kOff + c0 * 8);
    }
    __syncthreads();

#pragma unroll
    for (int kq = 0; kq < 2; ++kq) {
      bf16x8 af[4], bfq[4];
      const int lg = kq * 4 + qd;
#pragma unroll
      for (int mt = 0; mt < 4; ++mt) {
        const int r = wrow + mt * 16 + lq;
        af[mt] = *reinterpret_cast<const bf16x8*>(&As[r * 64 + (lg ^ (r & 7)) * 8]);
      }
#pragma unroll
      for (int nt = 0; nt < 4; ++nt) {
        const int r = wcol + nt * 16 + lq;
        bfq[nt] = *reinterpret_cast<const bf16x8*>(&Bs[r * 64 + (lg ^ (r & 7)) * 8]);
      }
#pragma unroll
      for (int mt = 0; mt < 4; ++mt)
#pragma unroll
        for (int nt = 0; nt < 4; ++nt)
          c[mt][nt] = __builtin_amdgcn_mfma_f32_16x16x32_bf16(af[mt], bfq[nt], c[mt][nt], 0, 0, 0);
    }
  }

  // ---- epilogue (R6-identical): e = exp(sim-20); pos gated by ad match ----
  float colB[4];
  int colAd[4];
#pragma unroll
  for (int nt = 0; nt < 4; ++nt) {
    const int col = colBase + wcol + nt * 16 + lq;
    colB[nt]  = SIM_BIAS + cbias[col];
    colAd[nt] = ad[col];
  }

  __syncthreads();  // all waves done with As/Bs before reuse as partials

  const int idx = (w & 1) * 16 + lq;   // 32 partials per row
  const int g   = idx >> 2;
  const int gi  = idx & 3;

#pragma unroll
  for (int mt = 0; mt < 4; ++mt) {
#pragma unroll
    for (int r = 0; r < 4; ++r) {
      const int row   = wrow + mt * 16 + qd * 4 + r;
      const int rowAd = ad[rowBase + row];
      float a = 0.f, p = 0.f;
#pragma unroll
      for (int nt = 0; nt < 4; ++nt) {
        const float e = __builtin_amdgcn_exp2f(fmaf(c[mt][nt][r], SIM_SCALE, colB[nt]));
        a += e;
        p += (colAd[nt] == rowAd) ? e : 0.f;
      }
      const int off = row * 32 + ((g ^ (row & 7)) << 2) + gi;
      redA[off] = a;
      redP[off] = p;
    }
  }
  __syncthreads();

  if (tid < 128) {
    const int row = tid;
    float a = 0.f, p = 0.f;
#pragma unroll
    for (int gg = 0; gg < 8; ++gg) {
      const int off = row * 32 + ((gg ^ (row & 7)) << 2);
      const f32x4 va = *reinterpret_cast<const f32x4*>(&redA[off]);
      const f32x4 vp = *reinterpret_cast<const f32x4*>(&redP[off]);
      a += (va[0] + va[1]) + (va[2] + va[3]);
      p += (vp[0] + vp[1]) + (vp[2] + vp[3]);
    }
    atomicAdd(&g_all[rowBase + row], a);
    atomicAdd(&g_pos[rowBase + row], p);
  }

  // ---- finalize: last block to finish computes the loss (fence-free) ----
  __syncthreads();  // drains vmcnt(0): this block's atomics are complete
  __shared__ int isLast;
  if (tid == 0)
    isLast = (__hip_atomic_fetch_add(done, 1u, __ATOMIC_RELAXED,
                                     __HIP_MEMORY_SCOPE_AGENT) == NBLK - 1u) ? 1 : 0;
  __syncthreads();
  if (isLast) {
    __shared__ float sS[4], sC[4];
    float s = 0.f, cctr = 0.f;
    for (int i = tid; i < Nn; i += 256) {
      if (cbias[i] == 0.0f) {            // valid row
        const float a = __hip_atomic_load(&g_all[i], __ATOMIC_RELAXED, __HIP_MEMORY_SCOPE_AGENT);
        const float p = __hip_atomic_load(&g_pos[i], __ATOMIC_RELAXED, __HIP_MEMORY_SCOPE_AGENT);
        s += __logf(a) - __logf(p);
        cctr += 1.0f;
      }
    }
#pragma unroll
    for (int m = 32; m >= 1; m >>= 1) {
      s += __shfl_xor(s, m);
      cctr += __shfl_xor(cctr, m);
    }
    if (lane == 0) { sS[w] = s; sC[w] = cctr; }
    __syncthreads();
    if (tid == 0) {
      const float S = sS[0] + sS[1] + sS[2] + sS[3];
      const float C = sC[0] + sC[1] + sC[2] + sC[3];
      out[0] = S / fmaxf(C, 1.0f);
    }
  }
}

extern "C" void kernel_launch(void* const* d_in, const int* in_sizes, int n_in,
                              void* d_out, int out_size, void* d_ws, size_t ws_size,
                              hipStream_t stream) {
  const float* logits = (const float*)d_in[0];
  const float* labels = (const float*)d_in[1];
  const int*   pad    = (const int*)d_in[2];
  const int*   ad     = (const int*)d_in[3];

  char* ws = (char*)d_ws;
  __bf16* qb   = (__bf16*)(ws);                 // 4 MiB
  __bf16* kb   = (__bf16*)(ws + 4194304);       // 4 MiB
  float*  cb   = (float*)(ws + 8388608);        // 32 KiB
  float*  gAll = (float*)(ws + 8421376);        // 32 KiB
  float*  gPos = (float*)(ws + 8454144);        // 32 KiB
  unsigned int* done = (unsigned int*)(ws + 8486912);
  float*  out  = (float*)d_out;

  prep_kernel<<<4096, 256, 0, stream>>>(logits, labels, pad, qb, kb, cb, gAll, gPos, done);
  gemm_lse_kernel<<<dim3(64, 64), 256, 0, stream>>>(qb, kb, cb, ad, gAll, gPos, done, out);
}

// Round 11
// 120.232 us; speedup vs baseline: 3.1943x; 1.4049x over previous
//
#include <hip/hip_runtime.h>
#include <hip/hip_bf16.h>
#include <math.h>

typedef __bf16 bf16x8 __attribute__((ext_vector_type(8)));
typedef __bf16 bf16x4 __attribute__((ext_vector_type(4)));
typedef float  f32x4  __attribute__((ext_vector_type(4)));

constexpr int Nn = 8192;   // B*S
constexpr int Dd = 256;    // feature dim
constexpr float LOG2E     = 1.4426950408889634f;
constexpr float SIM_SCALE = 20.0f * LOG2E;   // (1/tau)*log2(e), tau=0.05
constexpr float SIM_BIAS  = -20.0f * LOG2E;  // fixed max = 1/tau (|q.k|<=1)

// async global->LDS DMA, 16B/lane; LDS dst = wave-uniform base + lane*16.
// Verified correct in R5 (passed, absmax 0.0).
typedef __attribute__((address_space(1))) const unsigned int gu32;
typedef __attribute__((address_space(3))) unsigned int lu32;
__device__ __forceinline__ void gload16(const __bf16* g, __bf16* l) {
  __builtin_amdgcn_global_load_lds((gu32*)(uintptr_t)g, (lu32*)(uintptr_t)l, 16, 0, 0);
}

// ---------------------------------------------------------------------------
// Kernel 1: L2-normalize rows -> bf16; init cbias / g_all / g_pos.
// ---------------------------------------------------------------------------
__global__ __launch_bounds__(256) void prep_kernel(const float* __restrict__ logits,
                                                   const float* __restrict__ labels,
                                                   const int* __restrict__ pad,
                                                   __bf16* __restrict__ qb,
                                                   __bf16* __restrict__ kb,
                                                   float* __restrict__ cbias,
                                                   float* __restrict__ g_all,
                                                   float* __restrict__ g_pos) {
  const int j = blockIdx.x * 256 + threadIdx.x;
  if (j < Nn) {
    cbias[j] = pad[j] ? 0.0f : -1e30f;
    g_all[j] = 0.0f;
    g_pos[j] = 0.0f;
  }

  const int gw   = (blockIdx.x * 256 + threadIdx.x) >> 6;
  const int lane = threadIdx.x & 63;
  const float* src;
  __bf16* dst;
  int row;
  if (gw < Nn) { src = logits; dst = qb; row = gw; }
  else         { src = labels; dst = kb; row = gw - Nn; }

  const float4 v = *reinterpret_cast<const float4*>(src + (size_t)row * Dd + lane * 4);
  float ss = v.x * v.x + v.y * v.y + v.z * v.z + v.w * v.w;
#pragma unroll
  for (int m = 32; m >= 1; m >>= 1) ss += __shfl_xor(ss, m);
  const float scale = 1.0f / fmaxf(sqrtf(ss), 1e-12f);

  bf16x4 o;
  o[0] = (__bf16)(v.x * scale);
  o[1] = (__bf16)(v.y * scale);
  o[2] = (__bf16)(v.z * scale);
  o[3] = (__bf16)(v.w * scale);
  *reinterpret_cast<bf16x4*>(dst + (size_t)row * Dd + lane * 4) = o;
}

// ---------------------------------------------------------------------------
// Kernel 2: fused sim = Q K^T / tau + dual exp-sum epilogue (all & pos).
// R6 structure (59.9 us verified) with ONE change: staging via
// global_load_lds DMA (R5-verified pattern) -- deletes the 8 ds_write_b128
// wave-slots per K-chunk (LDS-issue was the computed bottleneck:
// 24 LDS instr x ~12cyc = 288 cyc vs 155 cyc MFMA per wave per chunk).
// No finalize fusion (R10: it poisoned regalloc, 2x slowdown).
// ---------------------------------------------------------------------------
__global__ __launch_bounds__(256) void gemm_lse_kernel(const __bf16* __restrict__ qb,
                                                       const __bf16* __restrict__ kb,
                                                       const float* __restrict__ cbias,
                                                       const int* __restrict__ ad,
                                                       float* __restrict__ g_all,
                                                       float* __restrict__ g_pos) {
  __shared__ __bf16 smem[2 * 128 * 64];  // 32 KiB: As | Bs, reused by epilogue
  __bf16* As = smem;
  __bf16* Bs = smem + 128 * 64;
  float* redA = reinterpret_cast<float*>(smem);         // 128 x 32 partials
  float* redP = reinterpret_cast<float*>(smem) + 4096;  // 128 x 32 partials

  const int tid  = threadIdx.x;
  const int lane = tid & 63;
  const int w    = tid >> 6;
  const int wrow = (w >> 1) * 64;
  const int wcol = (w & 1) * 64;
  const int lq   = lane & 15;
  const int qd   = lane >> 4;
  const int rowBase = blockIdx.x * 128;
  const int colBase = blockIdx.y * 128;

  // per-lane staging constants (R5-verified): wave w, iter i fills LDS rows
  // [w*32+i*8, +8); lane l -> row +(l>>3), logical group (l&7)^(l>>3) lands
  // at the swizzled slot (group' = c ^ (row&7)) the read side expects.
  const int srl = lane >> 3;
  const int cg  = (lane & 7) ^ srl;
  const __bf16* gA0 = qb + (size_t)(rowBase + w * 32 + srl) * Dd + cg * 8;
  const __bf16* gB0 = kb + (size_t)(colBase + w * 32 + srl) * Dd + cg * 8;

  f32x4 c[4][4];
#pragma unroll
  for (int mt = 0; mt < 4; ++mt)
#pragma unroll
    for (int nt = 0; nt < 4; ++nt)
      c[mt][nt] = (f32x4){0.f, 0.f, 0.f, 0.f};

  for (int kk = 0; kk < 4; ++kk) {
    const int kOff = kk * 64;
    __syncthreads();  // prior MFMA phase done reading LDS
#pragma unroll
    for (int i = 0; i < 4; ++i) {
      gload16(gA0 + (size_t)i * 8 * Dd + kOff, &As[(w * 32 + i * 8) * 64]);
      gload16(gB0 + (size_t)i * 8 * Dd + kOff, &Bs[(w * 32 + i * 8) * 64]);
    }
    __syncthreads();  // drains vmcnt (DMA) before fragment reads

#pragma unroll
    for (int kq = 0; kq < 2; ++kq) {
      bf16x8 af[4], bfq[4];
      const int lg = kq * 4 + qd;  // logical 16B group within BK=64
#pragma unroll
      for (int mt = 0; mt < 4; ++mt) {
        const int r = wrow + mt * 16 + lq;
        af[mt] = *reinterpret_cast<const bf16x8*>(&As[r * 64 + (lg ^ (r & 7)) * 8]);
      }
#pragma unroll
      for (int nt = 0; nt < 4; ++nt) {
        const int r = wcol + nt * 16 + lq;
        bfq[nt] = *reinterpret_cast<const bf16x8*>(&Bs[r * 64 + (lg ^ (r & 7)) * 8]);
      }
#pragma unroll
      for (int mt = 0; mt < 4; ++mt)
#pragma unroll
        for (int nt = 0; nt < 4; ++nt)
          c[mt][nt] = __builtin_amdgcn_mfma_f32_16x16x32_bf16(af[mt], bfq[nt], c[mt][nt], 0, 0, 0);
    }
  }

  // ---- epilogue (R6-identical): e = exp(sim-20); pos gated by ad match ----
  float colB[4];
  int colAd[4];
#pragma unroll
  for (int nt = 0; nt < 4; ++nt) {
    const int col = colBase + wcol + nt * 16 + lq;
    colB[nt]  = SIM_BIAS + cbias[col];
    colAd[nt] = ad[col];
  }

  __syncthreads();  // all waves done with As/Bs before reuse as partials

  const int idx = (w & 1) * 16 + lq;   // 32 partials per row
  const int g   = idx >> 2;
  const int gi  = idx & 3;

#pragma unroll
  for (int mt = 0; mt < 4; ++mt) {
#pragma unroll
    for (int r = 0; r < 4; ++r) {
      const int row   = wrow + mt * 16 + qd * 4 + r;
      const int rowAd = ad[rowBase + row];
      float a = 0.f, p = 0.f;
#pragma unroll
      for (int nt = 0; nt < 4; ++nt) {
        const float e = __builtin_amdgcn_exp2f(fmaf(c[mt][nt][r], SIM_SCALE, colB[nt]));
        a += e;
        p += (colAd[nt] == rowAd) ? e : 0.f;
      }
      const int off = row * 32 + ((g ^ (row & 7)) << 2) + gi;
      redA[off] = a;
      redP[off] = p;
    }
  }
  __syncthreads();

  if (tid < 128) {
    const int row = tid;
    float a = 0.f, p = 0.f;
#pragma unroll
    for (int gg = 0; gg < 8; ++gg) {
      const int off = row * 32 + ((gg ^ (row & 7)) << 2);
      const f32x4 va = *reinterpret_cast<const f32x4*>(&redA[off]);
      const f32x4 vp = *reinterpret_cast<const f32x4*>(&redP[off]);
      a += (va[0] + va[1]) + (va[2] + va[3]);
      p += (vp[0] + vp[1]) + (vp[2] + vp[3]);
    }
    atomicAdd(&g_all[rowBase + row], a);
    atomicAdd(&g_pos[rowBase + row], p);
  }
}

// ---------------------------------------------------------------------------
// Kernel 3: loss = mean over valid rows of log(g_all) - log(g_pos).
// ---------------------------------------------------------------------------
__global__ __launch_bounds__(1024) void reduce_kernel(const float* __restrict__ g_all,
                                                      const float* __restrict__ g_pos,
                                                      const int* __restrict__ pad,
                                                      float* __restrict__ out) {
  __shared__ float sS[16], sC[16];
  const int t = threadIdx.x;
  float s = 0.f, c = 0.f;
  const float4* ga4 = (const float4*)g_all;
  const float4* gp4 = (const float4*)g_pos;
  const int4*   pd4 = (const int4*)pad;
  for (int i = t; i < Nn / 4; i += 1024) {
    const float4 ga = ga4[i];
    const float4 gp = gp4[i];
    const int4   pd = pd4[i];
    if (pd.x) { s += __logf(ga.x) - __logf(gp.x); c += 1.f; }
    if (pd.y) { s += __logf(ga.y) - __logf(gp.y); c += 1.f; }
    if (pd.z) { s += __logf(ga.z) - __logf(gp.z); c += 1.f; }
    if (pd.w) { s += __logf(ga.w) - __logf(gp.w); c += 1.f; }
  }
#pragma unroll
  for (int m = 32; m >= 1; m >>= 1) {
    s += __shfl_xor(s, m);
    c += __shfl_xor(c, m);
  }
  if ((t & 63) == 0) { sS[t >> 6] = s; sC[t >> 6] = c; }
  __syncthreads();
  if (t == 0) {
    float S = 0.f, C = 0.f;
#pragma unroll
    for (int i = 0; i < 16; ++i) { S += sS[i]; C += sC[i]; }
    out[0] = S / fmaxf(C, 1.0f);
  }
}

extern "C" void kernel_launch(void* const* d_in, const int* in_sizes, int n_in,
                              void* d_out, int out_size, void* d_ws, size_t ws_size,
                              hipStream_t stream) {
  const float* logits = (const float*)d_in[0];
  const float* labels = (const float*)d_in[1];
  const int*   pad    = (const int*)d_in[2];
  const int*   ad     = (const int*)d_in[3];

  char* ws = (char*)d_ws;
  __bf16* qb   = (__bf16*)(ws);                 // 4 MiB
  __bf16* kb   = (__bf16*)(ws + 4194304);       // 4 MiB
  float*  cb   = (float*)(ws + 8388608);        // 32 KiB
  float*  gAll = (float*)(ws + 8421376);        // 32 KiB
  float*  gPos = (float*)(ws + 8454144);        // 32 KiB
  float*  out  = (float*)d_out;

  prep_kernel<<<4096, 256, 0, stream>>>(logits, labels, pad, qb, kb, cb, gAll, gPos);
  gemm_lse_kernel<<<dim3(64, 64), 256, 0, stream>>>(qb, kb, cb, ad, gAll, gPos);
  reduce_kernel<<<1, 1024, 0, stream>>>(gAll, gPos, pad, out);
}

// Round 12
// 113.532 us; speedup vs baseline: 3.3829x; 1.0590x over previous
//
#include <hip/hip_runtime.h>
#include <hip/hip_bf16.h>
#include <hip/hip_fp8.h>
#include <math.h>

typedef float f32x4 __attribute__((ext_vector_type(4)));

constexpr int Nn = 8192;   // B*S
constexpr int Dd = 256;    // feature dim (== bytes per fp8 row)
constexpr float LOG2E     = 1.4426950408889634f;
constexpr float SIM_SCALE = 20.0f * LOG2E;   // (1/tau)*log2(e), tau=0.05
constexpr float SIM_BIAS  = -20.0f * LOG2E;  // fixed max = 1/tau (|q.k|<=1)

// async global->LDS DMA, 16B/lane; LDS dst = wave-uniform base + lane*16.
// (R5/R11-verified path.)
typedef __attribute__((address_space(1))) const unsigned int gu32;
typedef __attribute__((address_space(3))) unsigned int lu32;
__device__ __forceinline__ void gload16(const unsigned char* g, unsigned char* l) {
  __builtin_amdgcn_global_load_lds((gu32*)(uintptr_t)g, (lu32*)(uintptr_t)l, 16, 0, 0);
}

// ---------------------------------------------------------------------------
// Kernel 1: L2-normalize rows -> fp8 e4m3 (OCP); init cbias / g_all / g_pos.
// ---------------------------------------------------------------------------
__global__ __launch_bounds__(256) void prep_kernel(const float* __restrict__ logits,
                                                   const float* __restrict__ labels,
                                                   const int* __restrict__ pad,
                                                   unsigned char* __restrict__ qb,
                                                   unsigned char* __restrict__ kb,
                                                   float* __restrict__ cbias,
                                                   float* __restrict__ g_all,
                                                   float* __restrict__ g_pos) {
  const int j = blockIdx.x * 256 + threadIdx.x;
  if (j < Nn) {
    cbias[j] = pad[j] ? 0.0f : -1e30f;
    g_all[j] = 0.0f;
    g_pos[j] = 0.0f;
  }

  const int gw   = (blockIdx.x * 256 + threadIdx.x) >> 6;
  const int lane = threadIdx.x & 63;
  const float* src;
  unsigned char* dst;
  int row;
  if (gw < Nn) { src = logits; dst = qb; row = gw; }
  else         { src = labels; dst = kb; row = gw - Nn; }

  const float4 v = *reinterpret_cast<const float4*>(src + (size_t)row * Dd + lane * 4);
  float ss = v.x * v.x + v.y * v.y + v.z * v.z + v.w * v.w;
#pragma unroll
  for (int m = 32; m >= 1; m >>= 1) ss += __shfl_xor(ss, m);
  const float scale = 1.0f / fmaxf(sqrtf(ss), 1e-12f);

  const __hip_fp8_e4m3 e0(v.x * scale);
  const __hip_fp8_e4m3 e1(v.y * scale);
  const __hip_fp8_e4m3 e2(v.z * scale);
  const __hip_fp8_e4m3 e3(v.w * scale);
  const unsigned int packed = (unsigned int)e0.__x |
                              ((unsigned int)e1.__x << 8) |
                              ((unsigned int)e2.__x << 16) |
                              ((unsigned int)e3.__x << 24);
  reinterpret_cast<unsigned int*>(dst + (size_t)row * Dd)[lane] = packed;
}

// ---------------------------------------------------------------------------
// Kernel 2: fused sim = Q K^T / tau + dual exp-sum epilogue (all & pos), fp8.
// R11 structure with fp8 elements: BK=128 ELEMENTS = 128 B rows -> the LDS
// geometry (swizzle group' = c ^ (row&7), staging constants (l&7)^(l>>3))
// is byte-identical to the verified bf16 kernel; only 2 K-chunks (half the
// barrier drains), fragment reads are ds_read_b64 (half the LDS-read issue,
// which was the binding pipe: 768 cyc vs 614 MFMA per wave), FETCH halves.
// MFMA: 16x16x32_fp8_fp8 (same rate as bf16, i64 operands).
// ---------------------------------------------------------------------------
__global__ __launch_bounds__(256) void gemm_lse_kernel(const unsigned char* __restrict__ qb,
                                                       const unsigned char* __restrict__ kb,
                                                       const float* __restrict__ cbias,
                                                       const int* __restrict__ ad,
                                                       float* __restrict__ g_all,
                                                       float* __restrict__ g_pos) {
  __shared__ unsigned char smem[32768];  // As(16K) | Bs(16K); epilogue reuse
  unsigned char* As = smem;
  unsigned char* Bs = smem + 16384;
  float* redA = reinterpret_cast<float*>(smem);         // 128 x 32 partials
  float* redP = reinterpret_cast<float*>(smem) + 4096;  // 128 x 32 partials

  const int tid  = threadIdx.x;
  const int lane = tid & 63;
  const int w    = tid >> 6;
  const int wrow = (w >> 1) * 64;
  const int wcol = (w & 1) * 64;
  const int lq   = lane & 15;
  const int qd   = lane >> 4;
  const int rowBase = blockIdx.x * 128;
  const int colBase = blockIdx.y * 128;

  // staging constants (R5/R11-verified): wave w, iter i fills LDS rows
  // [w*32+i*8, +8); lane l -> row +(l>>3), logical 16B group (l&7)^(l>>3).
  const int srl = lane >> 3;
  const int cg  = (lane & 7) ^ srl;
  const unsigned char* gA0 = qb + (size_t)(rowBase + w * 32 + srl) * Dd + cg * 16;
  const unsigned char* gB0 = kb + (size_t)(colBase + w * 32 + srl) * Dd + cg * 16;

  f32x4 c[4][4];
#pragma unroll
  for (int mt = 0; mt < 4; ++mt)
#pragma unroll
    for (int nt = 0; nt < 4; ++nt)
      c[mt][nt] = (f32x4){0.f, 0.f, 0.f, 0.f};

  for (int kk = 0; kk < 2; ++kk) {
    const int kOff = kk * 128;  // byte offset into the 256 B row
    __syncthreads();  // prior MFMA phase done reading LDS
#pragma unroll
    for (int i = 0; i < 4; ++i) {
      gload16(gA0 + (size_t)i * 8 * Dd + kOff, &As[(w * 32 + i * 8) * 128]);
      gload16(gB0 + (size_t)i * 8 * Dd + kOff, &Bs[(w * 32 + i * 8) * 128]);
    }
    __syncthreads();  // drains vmcnt (DMA) before fragment reads

#pragma unroll
    for (int kq = 0; kq < 4; ++kq) {        // K=32 elems (=32 B) per step
      long av[4], bv[4];
      const int lg = kq * 2 + (qd >> 1);    // logical 16B group in 128B row
      const int bo = (qd & 1) * 8;          // byte half within the group
#pragma unroll
      for (int mt = 0; mt < 4; ++mt) {
        const int r = wrow + mt * 16 + lq;
        av[mt] = *reinterpret_cast<const long*>(&As[r * 128 + ((lg ^ (r & 7)) << 4) + bo]);
      }
#pragma unroll
      for (int nt = 0; nt < 4; ++nt) {
        const int r = wcol + nt * 16 + lq;
        bv[nt] = *reinterpret_cast<const long*>(&Bs[r * 128 + ((lg ^ (r & 7)) << 4) + bo]);
      }
#pragma unroll
      for (int mt = 0; mt < 4; ++mt)
#pragma unroll
        for (int nt = 0; nt < 4; ++nt)
          c[mt][nt] = __builtin_amdgcn_mfma_f32_16x16x32_fp8_fp8(av[mt], bv[nt], c[mt][nt], 0, 0, 0);
    }
  }

  // ---- epilogue (R6/R11-identical): e = exp(sim-20); pos gated by ad ----
  float colB[4];
  int colAd[4];
#pragma unroll
  for (int nt = 0; nt < 4; ++nt) {
    const int col = colBase + wcol + nt * 16 + lq;
    colB[nt]  = SIM_BIAS + cbias[col];
    colAd[nt] = ad[col];
  }

  __syncthreads();  // all waves done with As/Bs before reuse as partials

  const int idx = (w & 1) * 16 + lq;   // 32 partials per row
  const int g   = idx >> 2;
  const int gi  = idx & 3;

#pragma unroll
  for (int mt = 0; mt < 4; ++mt) {
#pragma unroll
    for (int r = 0; r < 4; ++r) {
      const int row   = wrow + mt * 16 + qd * 4 + r;
      const int rowAd = ad[rowBase + row];
      float a = 0.f, p = 0.f;
#pragma unroll
      for (int nt = 0; nt < 4; ++nt) {
        const float e = __builtin_amdgcn_exp2f(fmaf(c[mt][nt][r], SIM_SCALE, colB[nt]));
        a += e;
        p += (colAd[nt] == rowAd) ? e : 0.f;
      }
      const int off = row * 32 + ((g ^ (row & 7)) << 2) + gi;
      redA[off] = a;
      redP[off] = p;
    }
  }
  __syncthreads();

  if (tid < 128) {
    const int row = tid;
    float a = 0.f, p = 0.f;
#pragma unroll
    for (int gg = 0; gg < 8; ++gg) {
      const int off = row * 32 + ((gg ^ (row & 7)) << 2);
      const f32x4 va = *reinterpret_cast<const f32x4*>(&redA[off]);
      const f32x4 vp = *reinterpret_cast<const f32x4*>(&redP[off]);
      a += (va[0] + va[1]) + (va[2] + va[3]);
      p += (vp[0] + vp[1]) + (vp[2] + vp[3]);
    }
    atomicAdd(&g_all[rowBase + row], a);
    atomicAdd(&g_pos[rowBase + row], p);
  }
}

// ---------------------------------------------------------------------------
// Kernel 3: loss = mean over valid rows of log(g_all) - log(g_pos).
// ---------------------------------------------------------------------------
__global__ __launch_bounds__(1024) void reduce_kernel(const float* __restrict__ g_all,
                                                      const float* __restrict__ g_pos,
                                                      const int* __restrict__ pad,
                                                      float* __restrict__ out) {
  __shared__ float sS[16], sC[16];
  const int t = threadIdx.x;
  float s = 0.f, c = 0.f;
  const float4* ga4 = (const float4*)g_all;
  const float4* gp4 = (const float4*)g_pos;
  const int4*   pd4 = (const int4*)pad;
  for (int i = t; i < Nn / 4; i += 1024) {
    const float4 ga = ga4[i];
    const float4 gp = gp4[i];
    const int4   pd = pd4[i];
    if (pd.x) { s += __logf(ga.x) - __logf(gp.x); c += 1.f; }
    if (pd.y) { s += __logf(ga.y) - __logf(gp.y); c += 1.f; }
    if (pd.z) { s += __logf(ga.z) - __logf(gp.z); c += 1.f; }
    if (pd.w) { s += __logf(ga.w) - __logf(gp.w); c += 1.f; }
  }
#pragma unroll
  for (int m = 32; m >= 1; m >>= 1) {
    s += __shfl_xor(s, m);
    c += __shfl_xor(c, m);
  }
  if ((t & 63) == 0) { sS[t >> 6] = s; sC[t >> 6] = c; }
  __syncthreads();
  if (t == 0) {
    float S = 0.f, C = 0.f;
#pragma unroll
    for (int i = 0; i < 16; ++i) { S += sS[i]; C += sC[i]; }
    out[0] = S / fmaxf(C, 1.0f);
  }
}

extern "C" void kernel_launch(void* const* d_in, const int* in_sizes, int n_in,
                              void* d_out, int out_size, void* d_ws, size_t ws_size,
                              hipStream_t stream) {
  const float* logits = (const float*)d_in[0];
  const float* labels = (const float*)d_in[1];
  const int*   pad    = (const int*)d_in[2];
  const int*   ad     = (const int*)d_in[3];

  char* ws = (char*)d_ws;
  unsigned char* qb = (unsigned char*)(ws);             // 2 MiB (fp8)
  unsigned char* kb = (unsigned char*)(ws + 2097152);   // 2 MiB (fp8)
  float*  cb   = (float*)(ws + 4194304);                // 32 KiB
  float*  gAll = (float*)(ws + 4227072);                // 32 KiB
  float*  gPos = (float*)(ws + 4259840);                // 32 KiB
  float*  out  = (float*)d_out;

  prep_kernel<<<4096, 256, 0, stream>>>(logits, labels, pad, qb, kb, cb, gAll, gPos);
  gemm_lse_kernel<<<dim3(64, 64), 256, 0, stream>>>(qb, kb, cb, ad, gAll, gPos);
  reduce_kernel<<<1, 1024, 0, stream>>>(gAll, gPos, pad, out);
}

// Round 13
// 110.912 us; speedup vs baseline: 3.4628x; 1.0236x over previous
//
#include <hip/hip_runtime.h>
#include <hip/hip_bf16.h>
#include <hip/hip_fp8.h>
#include <math.h>

typedef float f32x4 __attribute__((ext_vector_type(4)));
typedef long  lx2   __attribute__((ext_vector_type(2)));

constexpr int Nn = 8192;   // B*S
constexpr int Dd = 256;    // feature dim (== bytes per fp8 row)
constexpr float LOG2E     = 1.4426950408889634f;
constexpr float SIM_SCALE = 20.0f * LOG2E;   // (1/tau)*log2(e), tau=0.05
constexpr float SIM_BIAS  = -20.0f * LOG2E;  // fixed max = 1/tau (|q.k|<=1)

// async global->LDS DMA, 16B/lane; LDS dst = wave-uniform base + lane*16.
// (R5/R11/R12-verified path.)
typedef __attribute__((address_space(1))) const unsigned int gu32;
typedef __attribute__((address_space(3))) unsigned int lu32;
__device__ __forceinline__ void gload16(const unsigned char* g, unsigned char* l) {
  __builtin_amdgcn_global_load_lds((gu32*)(uintptr_t)g, (lu32*)(uintptr_t)l, 16, 0, 0);
}

// ---------------------------------------------------------------------------
// Kernel 1: L2-normalize rows -> fp8 e4m3, stored K-PERMUTED per 128B half:
//   new = (o&128) + ((o>>3)&3)*32 + ((o>>5)&3)*8 + (o&7)
// so each MFMA lane's four 8B K-chunks (orig bytes qd*8 + 32*kq) become 32B
// contiguous (permuted groups 2qd, 2qd+1) -> fragment loads are ds_read_b128.
// Also init cbias / g_all / g_pos.
// ---------------------------------------------------------------------------
__global__ __launch_bounds__(256) void prep_kernel(const float* __restrict__ logits,
                                                   const float* __restrict__ labels,
                                                   const int* __restrict__ pad,
                                                   unsigned char* __restrict__ qb,
                                                   unsigned char* __restrict__ kb,
                                                   float* __restrict__ cbias,
                                                   float* __restrict__ g_all,
                                                   float* __restrict__ g_pos) {
  const int j = blockIdx.x * 256 + threadIdx.x;
  if (j < Nn) {
    cbias[j] = pad[j] ? 0.0f : -1e30f;
    g_all[j] = 0.0f;
    g_pos[j] = 0.0f;
  }

  const int gw   = (blockIdx.x * 256 + threadIdx.x) >> 6;
  const int lane = threadIdx.x & 63;
  const float* src;
  unsigned char* dst;
  int row;
  if (gw < Nn) { src = logits; dst = qb; row = gw; }
  else         { src = labels; dst = kb; row = gw - Nn; }

  const float4 v = *reinterpret_cast<const float4*>(src + (size_t)row * Dd + lane * 4);
  float ss = v.x * v.x + v.y * v.y + v.z * v.z + v.w * v.w;
#pragma unroll
  for (int m = 32; m >= 1; m >>= 1) ss += __shfl_xor(ss, m);
  const float scale = 1.0f / fmaxf(sqrtf(ss), 1e-12f);

  const __hip_fp8_e4m3 e0(v.x * scale);
  const __hip_fp8_e4m3 e1(v.y * scale);
  const __hip_fp8_e4m3 e2(v.z * scale);
  const __hip_fp8_e4m3 e3(v.w * scale);
  const unsigned int packed = (unsigned int)e0.__x |
                              ((unsigned int)e1.__x << 8) |
                              ((unsigned int)e2.__x << 16) |
                              ((unsigned int)e3.__x << 24);
  const int o = lane * 4;  // original byte offset in the 256B row
  const int newoff = (o & 128) + ((o >> 3) & 3) * 32 + ((o >> 5) & 3) * 8 + (o & 7);
  *reinterpret_cast<unsigned int*>(dst + (size_t)row * Dd + newoff) = packed;
}

// ---------------------------------------------------------------------------
// Kernel 2: fused sim = Q K^T / tau + dual exp-sum epilogue (all & pos), fp8.
// R12 structure with ONE change: fragment reads are ds_read_b128 on the
// K-permuted rows (2 reads/row/chunk, both 8B halves used) instead of 4
// ds_read_b64 -- R12's 4.7M bank-conflict cycles came from b64's 4-rows-per-
// bank-octet pattern; b128 reproduces the bf16 kernel's floor-level pattern.
// Staging DMA + swizzle (slot = g ^ (r&7)) byte-identical to R12.
// ---------------------------------------------------------------------------
__global__ __launch_bounds__(256) void gemm_lse_kernel(const unsigned char* __restrict__ qb,
                                                       const unsigned char* __restrict__ kb,
                                                       const float* __restrict__ cbias,
                                                       const int* __restrict__ ad,
                                                       float* __restrict__ g_all,
                                                       float* __restrict__ g_pos) {
  __shared__ unsigned char smem[32768];  // As(16K) | Bs(16K); epilogue reuse
  unsigned char* As = smem;
  unsigned char* Bs = smem + 16384;
  float* redA = reinterpret_cast<float*>(smem);         // 128 x 32 partials
  float* redP = reinterpret_cast<float*>(smem) + 4096;  // 128 x 32 partials

  const int tid  = threadIdx.x;
  const int lane = tid & 63;
  const int w    = tid >> 6;
  const int wrow = (w >> 1) * 64;
  const int wcol = (w & 1) * 64;
  const int lq   = lane & 15;
  const int qd   = lane >> 4;
  const int rowBase = blockIdx.x * 128;
  const int colBase = blockIdx.y * 128;

  // staging constants (R5/R11/R12-verified): wave w, iter i fills LDS rows
  // [w*32+i*8, +8); lane l -> row +(l>>3), logical 16B group (l&7)^(l>>3).
  const int srl = lane >> 3;
  const int cg  = (lane & 7) ^ srl;
  const unsigned char* gA0 = qb + (size_t)(rowBase + w * 32 + srl) * Dd + cg * 16;
  const unsigned char* gB0 = kb + (size_t)(colBase + w * 32 + srl) * Dd + cg * 16;

  f32x4 c[4][4];
#pragma unroll
  for (int mt = 0; mt < 4; ++mt)
#pragma unroll
    for (int nt = 0; nt < 4; ++nt)
      c[mt][nt] = (f32x4){0.f, 0.f, 0.f, 0.f};

  for (int kk = 0; kk < 2; ++kk) {
    const int kOff = kk * 128;  // byte offset into the 256 B row
    __syncthreads();  // prior MFMA phase done reading LDS
#pragma unroll
    for (int i = 0; i < 4; ++i) {
      gload16(gA0 + (size_t)i * 8 * Dd + kOff, &As[(w * 32 + i * 8) * 128]);
      gload16(gB0 + (size_t)i * 8 * Dd + kOff, &Bs[(w * 32 + i * 8) * 128]);
    }
    __syncthreads();  // drains vmcnt (DMA) before fragment reads

#pragma unroll
    for (int j = 0; j < 2; ++j) {       // permuted group 2qd+j: kq = 2j+{0,1}
      lx2 af[4], bfq[4];
      const int g = (qd << 1) + j;
#pragma unroll
      for (int mt = 0; mt < 4; ++mt) {
        const int r = wrow + mt * 16 + lq;
        af[mt] = *reinterpret_cast<const lx2*>(&As[r * 128 + ((g ^ (r & 7)) << 4)]);
      }
#pragma unroll
      for (int nt = 0; nt < 4; ++nt) {
        const int r = wcol + nt * 16 + lq;
        bfq[nt] = *reinterpret_cast<const lx2*>(&Bs[r * 128 + ((g ^ (r & 7)) << 4)]);
      }
#pragma unroll
      for (int k2 = 0; k2 < 2; ++k2)
#pragma unroll
        for (int mt = 0; mt < 4; ++mt)
#pragma unroll
          for (int nt = 0; nt < 4; ++nt)
            c[mt][nt] = __builtin_amdgcn_mfma_f32_16x16x32_fp8_fp8(af[mt][k2], bfq[nt][k2],
                                                                   c[mt][nt], 0, 0, 0);
    }
  }

  // ---- epilogue (R6/R11/R12-identical): e = exp(sim-20); pos by ad match --
  float colB[4];
  int colAd[4];
#pragma unroll
  for (int nt = 0; nt < 4; ++nt) {
    const int col = colBase + wcol + nt * 16 + lq;
    colB[nt]  = SIM_BIAS + cbias[col];
    colAd[nt] = ad[col];
  }

  __syncthreads();  // all waves done with As/Bs before reuse as partials

  const int idx = (w & 1) * 16 + lq;   // 32 partials per row
  const int g   = idx >> 2;
  const int gi  = idx & 3;

#pragma unroll
  for (int mt = 0; mt < 4; ++mt) {
#pragma unroll
    for (int r = 0; r < 4; ++r) {
      const int row   = wrow + mt * 16 + qd * 4 + r;
      const int rowAd = ad[rowBase + row];
      float a = 0.f, p = 0.f;
#pragma unroll
      for (int nt = 0; nt < 4; ++nt) {
        const float e = __builtin_amdgcn_exp2f(fmaf(c[mt][nt][r], SIM_SCALE, colB[nt]));
        a += e;
        p += (colAd[nt] == rowAd) ? e : 0.f;
      }
      const int off = row * 32 + ((g ^ (row & 7)) << 2) + gi;
      redA[off] = a;
      redP[off] = p;
    }
  }
  __syncthreads();

  if (tid < 128) {
    const int row = tid;
    float a = 0.f, p = 0.f;
#pragma unroll
    for (int gg = 0; gg < 8; ++gg) {
      const int off = row * 32 + ((gg ^ (row & 7)) << 2);
      const f32x4 va = *reinterpret_cast<const f32x4*>(&redA[off]);
      const f32x4 vp = *reinterpret_cast<const f32x4*>(&redP[off]);
      a += (va[0] + va[1]) + (va[2] + va[3]);
      p += (vp[0] + vp[1]) + (vp[2] + vp[3]);
    }
    atomicAdd(&g_all[rowBase + row], a);
    atomicAdd(&g_pos[rowBase + row], p);
  }
}

// ---------------------------------------------------------------------------
// Kernel 3: loss = mean over valid rows of log(g_all) - log(g_pos).
// ---------------------------------------------------------------------------
__global__ __launch_bounds__(1024) void reduce_kernel(const float* __restrict__ g_all,
                                                      const float* __restrict__ g_pos,
                                                      const int* __restrict__ pad,
                                                      float* __restrict__ out) {
  __shared__ float sS[16], sC[16];
  const int t = threadIdx.x;
  float s = 0.f, c = 0.f;
  const float4* ga4 = (const float4*)g_all;
  const float4* gp4 = (const float4*)g_pos;
  const int4*   pd4 = (const int4*)pad;
  for (int i = t; i < Nn / 4; i += 1024) {
    const float4 ga = ga4[i];
    const float4 gp = gp4[i];
    const int4   pd = pd4[i];
    if (pd.x) { s += __logf(ga.x) - __logf(gp.x); c += 1.f; }
    if (pd.y) { s += __logf(ga.y) - __logf(gp.y); c += 1.f; }
    if (pd.z) { s += __logf(ga.z) - __logf(gp.z); c += 1.f; }
    if (pd.w) { s += __logf(ga.w) - __logf(gp.w); c += 1.f; }
  }
#pragma unroll
  for (int m = 32; m >= 1; m >>= 1) {
    s += __shfl_xor(s, m);
    c += __shfl_xor(c, m);
  }
  if ((t & 63) == 0) { sS[t >> 6] = s; sC[t >> 6] = c; }
  __syncthreads();
  if (t == 0) {
    float S = 0.f, C = 0.f;
#pragma unroll
    for (int i = 0; i < 16; ++i) { S += sS[i]; C += sC[i]; }
    out[0] = S / fmaxf(C, 1.0f);
  }
}

extern "C" void kernel_launch(void* const* d_in, const int* in_sizes, int n_in,
                              void* d_out, int out_size, void* d_ws, size_t ws_size,
                              hipStream_t stream) {
  const float* logits = (const float*)d_in[0];
  const float* labels = (const float*)d_in[1];
  const int*   pad    = (const int*)d_in[2];
  const int*   ad     = (const int*)d_in[3];

  char* ws = (char*)d_ws;
  unsigned char* qb = (unsigned char*)(ws);             // 2 MiB (fp8)
  unsigned char* kb = (unsigned char*)(ws + 2097152);   // 2 MiB (fp8)
  float*  cb   = (float*)(ws + 4194304);                // 32 KiB
  float*  gAll = (float*)(ws + 4227072);                // 32 KiB
  float*  gPos = (float*)(ws + 4259840);                // 32 KiB
  float*  out  = (float*)d_out;

  prep_kernel<<<4096, 256, 0, stream>>>(logits, labels, pad, qb, kb, cb, gAll, gPos);
  gemm_lse_kernel<<<dim3(64, 64), 256, 0, stream>>>(qb, kb, cb, ad, gAll, gPos);
  reduce_kernel<<<1, 1024, 0, stream>>>(gAll, gPos, pad, out);
}

// Round 14
// 102.335 us; speedup vs baseline: 3.7530x; 1.0838x over previous
//
#include <hip/hip_runtime.h>
#include <hip/hip_bf16.h>
#include <hip/hip_fp8.h>
#include <math.h>

typedef float f32x4 __attribute__((ext_vector_type(4)));
typedef int   i32x4 __attribute__((ext_vector_type(4)));
typedef int   v8i   __attribute__((ext_vector_type(8)));

constexpr int Nn = 8192;   // B*S
constexpr int Dd = 256;    // feature dim (== bytes per fp8 row)
constexpr float LOG2E     = 1.4426950408889634f;
constexpr float SIM_SCALE = 20.0f * LOG2E;   // (1/tau)*log2(e), tau=0.05
constexpr float SIM_BIAS  = -20.0f * LOG2E;  // fixed max = 1/tau (|q.k|<=1)
constexpr int   SCALE1    = 0x7F7F7F7F;      // E8M0 127 = 2^0 in every byte

// async global->LDS DMA, 16B/lane; LDS dst = wave-uniform base + lane*16.
// (R5/R11/R12/R13-verified path.)
typedef __attribute__((address_space(1))) const unsigned int gu32;
typedef __attribute__((address_space(3))) unsigned int lu32;
__device__ __forceinline__ void gload16(const unsigned char* g, unsigned char* l) {
  __builtin_amdgcn_global_load_lds((gu32*)(uintptr_t)g, (lu32*)(uintptr_t)l, 16, 0, 0);
}

// ---------------------------------------------------------------------------
// Kernel 1: L2-normalize rows -> fp8 e4m3 (plain layout -- the scaled MFMA's
// A/B operand wants 32 contiguous K-bytes per lane, no permutation needed);
// init cbias / g_all / g_pos.
// ---------------------------------------------------------------------------
__global__ __launch_bounds__(256) void prep_kernel(const float* __restrict__ logits,
                                                   const float* __restrict__ labels,
                                                   const int* __restrict__ pad,
                                                   unsigned char* __restrict__ qb,
                                                   unsigned char* __restrict__ kb,
                                                   float* __restrict__ cbias,
                                                   float* __restrict__ g_all,
                                                   float* __restrict__ g_pos) {
  const int j = blockIdx.x * 256 + threadIdx.x;
  if (j < Nn) {
    cbias[j] = pad[j] ? 0.0f : -1e30f;
    g_all[j] = 0.0f;
    g_pos[j] = 0.0f;
  }

  const int gw   = (blockIdx.x * 256 + threadIdx.x) >> 6;
  const int lane = threadIdx.x & 63;
  const float* src;
  unsigned char* dst;
  int row;
  if (gw < Nn) { src = logits; dst = qb; row = gw; }
  else         { src = labels; dst = kb; row = gw - Nn; }

  const float4 v = *reinterpret_cast<const float4*>(src + (size_t)row * Dd + lane * 4);
  float ss = v.x * v.x + v.y * v.y + v.z * v.z + v.w * v.w;
#pragma unroll
  for (int m = 32; m >= 1; m >>= 1) ss += __shfl_xor(ss, m);
  const float scale = 1.0f / fmaxf(sqrtf(ss), 1e-12f);

  const __hip_fp8_e4m3 e0(v.x * scale);
  const __hip_fp8_e4m3 e1(v.y * scale);
  const __hip_fp8_e4m3 e2(v.z * scale);
  const __hip_fp8_e4m3 e3(v.w * scale);
  const unsigned int packed = (unsigned int)e0.__x |
                              ((unsigned int)e1.__x << 8) |
                              ((unsigned int)e2.__x << 16) |
                              ((unsigned int)e3.__x << 24);
  reinterpret_cast<unsigned int*>(dst + (size_t)row * Dd)[lane] = packed;
}

// ---------------------------------------------------------------------------
// Kernel 2: fused sim = Q K^T / tau + dual exp-sum epilogue (all & pos), fp8.
// R13 structure with ONE change: MX-scaled MFMA 16x16x128 (unit scales) --
// 32 MFMA instrs/wave instead of 128 (K=128/instr, 2.27x rate per ubench).
// Lane(lq,qd) operand = 32 contiguous K-bytes at qd*32 within the 128B
// chunk = swizzled groups {2qd, 2qd+1}: same 2x ds_read_b128 pattern and
// identical DMA staging/swizzle (slot = g ^ (r&7)) as R13.
// B-fragments loaded inside the nt-loop to cap live VGPRs (~40 + 64 acc).
// ---------------------------------------------------------------------------
__global__ __launch_bounds__(256) void gemm_lse_kernel(const unsigned char* __restrict__ qb,
                                                       const unsigned char* __restrict__ kb,
                                                       const float* __restrict__ cbias,
                                                       const int* __restrict__ ad,
                                                       float* __restrict__ g_all,
                                                       float* __restrict__ g_pos) {
  __shared__ unsigned char smem[32768];  // As(16K) | Bs(16K); epilogue reuse
  unsigned char* As = smem;
  unsigned char* Bs = smem + 16384;
  float* redA = reinterpret_cast<float*>(smem);         // 128 x 32 partials
  float* redP = reinterpret_cast<float*>(smem) + 4096;  // 128 x 32 partials

  const int tid  = threadIdx.x;
  const int lane = tid & 63;
  const int w    = tid >> 6;
  const int wrow = (w >> 1) * 64;
  const int wcol = (w & 1) * 64;
  const int lq   = lane & 15;
  const int qd   = lane >> 4;
  const int rowBase = blockIdx.x * 128;
  const int colBase = blockIdx.y * 128;

  // staging constants (verified): wave w, iter i fills LDS rows
  // [w*32+i*8, +8); lane l -> row +(l>>3), logical 16B group (l&7)^(l>>3).
  const int srl = lane >> 3;
  const int cg  = (lane & 7) ^ srl;
  const unsigned char* gA0 = qb + (size_t)(rowBase + w * 32 + srl) * Dd + cg * 16;
  const unsigned char* gB0 = kb + (size_t)(colBase + w * 32 + srl) * Dd + cg * 16;

  f32x4 c[4][4];
#pragma unroll
  for (int mt = 0; mt < 4; ++mt)
#pragma unroll
    for (int nt = 0; nt < 4; ++nt)
      c[mt][nt] = (f32x4){0.f, 0.f, 0.f, 0.f};

  for (int kk = 0; kk < 2; ++kk) {
    const int kOff = kk * 128;  // byte offset into the 256 B row
    __syncthreads();  // prior MFMA phase done reading LDS
#pragma unroll
    for (int i = 0; i < 4; ++i) {
      gload16(gA0 + (size_t)i * 8 * Dd + kOff, &As[(w * 32 + i * 8) * 128]);
      gload16(gB0 + (size_t)i * 8 * Dd + kOff, &Bs[(w * 32 + i * 8) * 128]);
    }
    __syncthreads();  // drains vmcnt (DMA) before fragment reads

    const int g0 = qd << 1;  // lane's first 16B group (K bytes qd*32..+15)
    v8i af[4];
#pragma unroll
    for (int mt = 0; mt < 4; ++mt) {
      const int r = wrow + mt * 16 + lq;
      const i32x4 lo = *reinterpret_cast<const i32x4*>(&As[r * 128 + ((g0 ^ (r & 7)) << 4)]);
      const i32x4 hi = *reinterpret_cast<const i32x4*>(&As[r * 128 + (((g0 + 1) ^ (r & 7)) << 4)]);
      af[mt] = (v8i){lo.x, lo.y, lo.z, lo.w, hi.x, hi.y, hi.z, hi.w};
    }
#pragma unroll
    for (int nt = 0; nt < 4; ++nt) {
      const int r = wcol + nt * 16 + lq;
      const i32x4 lo = *reinterpret_cast<const i32x4*>(&Bs[r * 128 + ((g0 ^ (r & 7)) << 4)]);
      const i32x4 hi = *reinterpret_cast<const i32x4*>(&Bs[r * 128 + (((g0 + 1) ^ (r & 7)) << 4)]);
      const v8i bfq = (v8i){lo.x, lo.y, lo.z, lo.w, hi.x, hi.y, hi.z, hi.w};
#pragma unroll
      for (int mt = 0; mt < 4; ++mt)
        c[mt][nt] = __builtin_amdgcn_mfma_scale_f32_16x16x128_f8f6f4(
            af[mt], bfq, c[mt][nt], 0, 0, 0, SCALE1, 0, SCALE1);
    }
  }

  // ---- epilogue (R6/R11/R12/R13-identical) ----
  float colB[4];
  int colAd[4];
#pragma unroll
  for (int nt = 0; nt < 4; ++nt) {
    const int col = colBase + wcol + nt * 16 + lq;
    colB[nt]  = SIM_BIAS + cbias[col];
    colAd[nt] = ad[col];
  }

  __syncthreads();  // all waves done with As/Bs before reuse as partials

  const int idx = (w & 1) * 16 + lq;   // 32 partials per row
  const int g   = idx >> 2;
  const int gi  = idx & 3;

#pragma unroll
  for (int mt = 0; mt < 4; ++mt) {
#pragma unroll
    for (int r = 0; r < 4; ++r) {
      const int row   = wrow + mt * 16 + qd * 4 + r;
      const int rowAd = ad[rowBase + row];
      float a = 0.f, p = 0.f;
#pragma unroll
      for (int nt = 0; nt < 4; ++nt) {
        const float e = __builtin_amdgcn_exp2f(fmaf(c[mt][nt][r], SIM_SCALE, colB[nt]));
        a += e;
        p += (colAd[nt] == rowAd) ? e : 0.f;
      }
      const int off = row * 32 + ((g ^ (row & 7)) << 2) + gi;
      redA[off] = a;
      redP[off] = p;
    }
  }
  __syncthreads();

  if (tid < 128) {
    const int row = tid;
    float a = 0.f, p = 0.f;
#pragma unroll
    for (int gg = 0; gg < 8; ++gg) {
      const int off = row * 32 + ((gg ^ (row & 7)) << 2);
      const f32x4 va = *reinterpret_cast<const f32x4*>(&redA[off]);
      const f32x4 vp = *reinterpret_cast<const f32x4*>(&redP[off]);
      a += (va[0] + va[1]) + (va[2] + va[3]);
      p += (vp[0] + vp[1]) + (vp[2] + vp[3]);
    }
    atomicAdd(&g_all[rowBase + row], a);
    atomicAdd(&g_pos[rowBase + row], p);
  }
}

// ---------------------------------------------------------------------------
// Kernel 3: loss = mean over valid rows of log(g_all) - log(g_pos).
// ---------------------------------------------------------------------------
__global__ __launch_bounds__(1024) void reduce_kernel(const float* __restrict__ g_all,
                                                      const float* __restrict__ g_pos,
                                                      const int* __restrict__ pad,
                                                      float* __restrict__ out) {
  __shared__ float sS[16], sC[16];
  const int t = threadIdx.x;
  float s = 0.f, c = 0.f;
  const float4* ga4 = (const float4*)g_all;
  const float4* gp4 = (const float4*)g_pos;
  const int4*   pd4 = (const int4*)pad;
  for (int i = t; i < Nn / 4; i += 1024) {
    const float4 ga = ga4[i];
    const float4 gp = gp4[i];
    const int4   pd = pd4[i];
    if (pd.x) { s += __logf(ga.x) - __logf(gp.x); c += 1.f; }
    if (pd.y) { s += __logf(ga.y) - __logf(gp.y); c += 1.f; }
    if (pd.z) { s += __logf(ga.z) - __logf(gp.z); c += 1.f; }
    if (pd.w) { s += __logf(ga.w) - __logf(gp.w); c += 1.f; }
  }
#pragma unroll
  for (int m = 32; m >= 1; m >>= 1) {
    s += __shfl_xor(s, m);
    c += __shfl_xor(c, m);
  }
  if ((t & 63) == 0) { sS[t >> 6] = s; sC[t >> 6] = c; }
  __syncthreads();
  if (t == 0) {
    float S = 0.f, C = 0.f;
#pragma unroll
    for (int i = 0; i < 16; ++i) { S += sS[i]; C += sC[i]; }
    out[0] = S / fmaxf(C, 1.0f);
  }
}

extern "C" void kernel_launch(void* const* d_in, const int* in_sizes, int n_in,
                              void* d_out, int out_size, void* d_ws, size_t ws_size,
                              hipStream_t stream) {
  const float* logits = (const float*)d_in[0];
  const float* labels = (const float*)d_in[1];
  const int*   pad    = (const int*)d_in[2];
  const int*   ad     = (const int*)d_in[3];

  char* ws = (char*)d_ws;
  unsigned char* qb = (unsigned char*)(ws);             // 2 MiB (fp8)
  unsigned char* kb = (unsigned char*)(ws + 2097152);   // 2 MiB (fp8)
  float*  cb   = (float*)(ws + 4194304);                // 32 KiB
  float*  gAll = (float*)(ws + 4227072);                // 32 KiB
  float*  gPos = (float*)(ws + 4259840);                // 32 KiB
  float*  out  = (float*)d_out;

  prep_kernel<<<4096, 256, 0, stream>>>(logits, labels, pad, qb, kb, cb, gAll, gPos);
  gemm_lse_kernel<<<dim3(64, 64), 256, 0, stream>>>(qb, kb, cb, ad, gAll, gPos);
  reduce_kernel<<<1, 1024, 0, stream>>>(gAll, gPos, pad, out);
}